// Round 5
// baseline (253.346 us; speedup 1.0000x reference)
//
#include <hip/hip_runtime.h>

// inputs: (B=8, C=2, D=96, H=64, W=64) f32
// weight/bias: (F=8, C=2, d=3, h=60, w=64) f32
// out: (B=8, F=8, Dout=94, h=60, w=64) f32
#define B_ 8
#define C_ 2
#define D_ 96
#define H_ 64
#define W_ 64
#define F_ 8
#define KD 3
#define h_ 60
#define Dout_ 94
#define PLANE (h_ * W_)       // 3840 floats
#define NCH (PLANE / 4)       // 960 float4 per output plane
#define INCH (H_ * W_ / 4)    // 1024 float4 per input plane
#define NT 320                // threads in k_main: 960 = 320*3 exact

__device__ __forceinline__ float4 f4fma(float4 a, float4 b, float4 c) {
    c.x += a.x * b.x; c.y += a.y * b.y; c.z += a.z * b.z; c.w += a.w * b.w;
    return c;
}
__device__ __forceinline__ float4 f4add3(float4 a, float4 b, float4 c) {
    float4 o;
    o.x = a.x + b.x + c.x; o.y = a.y + b.y + c.y;
    o.z = a.z + b.z + c.z; o.w = a.w + b.w + c.w;
    return o;
}

// Horizontal 3-tap sum via lane shuffles; c4 = float4-column 0..15 within a
// 16-lane row group (rows never straddle a 16-lane group since 64|16).
// Boundary columns contribute zero. Call from ALL lanes.
__device__ __forceinline__ float4 hsum3(float4 V, int c4) {
    const int lane = threadIdx.x & 63;
    float lw = __shfl(V.w, (lane + 63) & 63, 64);
    float rx = __shfl(V.x, (lane + 1) & 63, 64);
    if (c4 == 0) lw = 0.f;
    if (c4 == 15) rx = 0.f;
    float4 o;
    o.x = lw + V.x + V.y;
    o.y = V.x + V.y + V.z;
    o.z = V.y + V.z + V.w;
    o.w = V.z + V.w + rx;
    return o;
}

// ---------------------------------------------------------------------------
// bb[f] = Box3x3( sum_{c,z} bias[f,c,z] )  (unscaled). 8 blocks.
// ---------------------------------------------------------------------------
__global__ __launch_bounds__(256) void k_bb(const float* __restrict__ bs,
                                            float* __restrict__ bb) {
    const int f = blockIdx.x;
    const int tid = threadIdx.x;
    __shared__ float4 R[62 * 16];  // rows 0 and 61 zeroed
    if (tid < 32) {
        const int r = (tid >> 4) ? 61 : 0;
        R[r * 16 + (tid & 15)] = make_float4(0, 0, 0, 0);
    }
    const float4* bp = (const float4*)(bs + (size_t)f * (C_ * KD * PLANE));
#pragma unroll
    for (int k = 0; k < 4; ++k) {
        const int e = tid + 256 * k;
        if (e < NCH) {
            float4 s = make_float4(0, 0, 0, 0);
#pragma unroll
            for (int s6 = 0; s6 < 6; ++s6) {
                const float4 v = bp[s6 * NCH + e];
                s.x += v.x; s.y += v.y; s.z += v.z; s.w += v.w;
            }
            R[((e >> 4) + 1) * 16 + (e & 15)] = s;
        }
    }
    __syncthreads();
    float4* ob = (float4*)(bb + (size_t)f * PLANE);
#pragma unroll
    for (int k = 0; k < 4; ++k) {
        const int e = tid + 256 * k;
        float4 V = make_float4(0, 0, 0, 0);
        int c4 = e & 15;
        if (e < NCH) {
            const int row = e >> 4;
            V = f4add3(R[row * 16 + c4], R[(row + 1) * 16 + c4],
                       R[(row + 2) * 16 + c4]);
        }
        float4 o = hsum3(V, c4);       // uniform call
        if (e < NCH) ob[e] = o;
    }
}

// ---------------------------------------------------------------------------
// Main kernel. Block = (b, dout); 320 threads; 752 blocks.
// Phase 1: stage 6 input planes via ping-pong LDS, build S2 (vertical 5-sum)
//          in 18 float4 registers — input read ONCE per (b,dout).
// Phase 2: loop f=0..7: weights streamed from (XCD-resident) L2, FMA vs
//          register S2, 3x3 box via ping-pong LDS (1 barrier/f) + shuffles,
//          +bb, *0.25, leaky-relu, ONE contiguous full-plane store per f.
// ---------------------------------------------------------------------------
__global__ __launch_bounds__(NT) void k_main(const float* __restrict__ in,
                                             const float* __restrict__ wt,
                                             const float* __restrict__ bb,
                                             float* __restrict__ out) {
    const int bx = blockIdx.x;
    const int dout = bx % Dout_;
    const int b = bx / Dout_;
    const int tid = threadIdx.x;

    __shared__ float4 L[2][INCH];   // 32 KB, reused: input staging then box

    int e[3], c4[3], row[3];
#pragma unroll
    for (int k = 0; k < 3; ++k) {
        e[k] = tid + NT * k;        // 0..959
        row[k] = e[k] >> 4;         // 0..59
        c4[k] = e[k] & 15;
    }

    // ---- Phase 1: S2 into registers ----
    float4 s2r[6][3];               // [c*3+z][chunk]
    const float4* in4 = (const float4*)in;
#pragma unroll
    for (int c = 0; c < C_; ++c)
#pragma unroll
        for (int z = 0; z < KD; ++z) {
            const int p = c * KD + z;
            const size_t pb = ((size_t)(b * C_ + c) * D_ + (dout + z)) * INCH;
            float4* Ls = L[p & 1];
#pragma unroll
            for (int k2 = 0; k2 < 4; ++k2) {
                const int idx = tid + NT * k2;
                if (idx < INCH) Ls[idx] = in4[pb + idx];
            }
            __syncthreads();
#pragma unroll
            for (int k = 0; k < 3; ++k) {
                float4 s = Ls[row[k] * 16 + c4[k]];
#pragma unroll
                for (int j = 1; j < 5; ++j) {
                    const float4 v = Ls[(row[k] + j) * 16 + c4[k]];
                    s.x += v.x; s.y += v.y; s.z += v.z; s.w += v.w;
                }
                s2r[p][k] = s;
            }
        }

    // ---- Phase 2: f-loop ----
    const float4* wt4 = (const float4*)wt;
    const float4* bb4 = (const float4*)bb;
    float4* out4 = (float4*)out;
    const float4 z4 = make_float4(0, 0, 0, 0);

    for (int f = 0; f < F_; ++f) {
        float4 acc[3];
#pragma unroll
        for (int k = 0; k < 3; ++k) acc[k] = z4;

#pragma unroll
        for (int c = 0; c < C_; ++c)
#pragma unroll
            for (int z = 0; z < KD; ++z) {
                const size_t wb = (size_t)((f * C_ + c) * KD + z) * NCH;
#pragma unroll
                for (int k = 0; k < 3; ++k) {
                    const float4 w = wt4[wb + e[k]];
                    acc[k] = f4fma(w, s2r[c * KD + z][k], acc[k]);
                }
            }

        float4 bbv[3];
#pragma unroll
        for (int k = 0; k < 3; ++k)
            bbv[k] = bb4[(size_t)f * NCH + e[k]];

        // Box buffer: rows 0..61 (992 entries of the 1024-slot buffer).
        float4* Lb = L[f & 1];
        if (f < 2 && tid < 32) {    // zero halo rows once per buffer
            const int r = (tid >> 4) ? 61 : 0;
            Lb[r * 16 + (tid & 15)] = z4;
        }
#pragma unroll
        for (int k = 0; k < 3; ++k)
            Lb[(row[k] + 1) * 16 + c4[k]] = acc[k];
        __syncthreads();            // the single barrier per f

        const size_t ob = ((size_t)(b * F_ + f) * Dout_ + dout) * NCH;
#pragma unroll
        for (int k = 0; k < 3; ++k) {
            const float4 V = f4add3(Lb[row[k] * 16 + c4[k]],
                                    Lb[(row[k] + 1) * 16 + c4[k]],
                                    Lb[(row[k] + 2) * 16 + c4[k]]);
            float4 o = hsum3(V, c4[k]);
            o.x = 0.25f * (o.x + bbv[k].x);
            o.y = 0.25f * (o.y + bbv[k].y);
            o.z = 0.25f * (o.z + bbv[k].z);
            o.w = 0.25f * (o.w + bbv[k].w);
            o.x = (o.x > 0.f) ? o.x : 0.2f * o.x;
            o.y = (o.y > 0.f) ? o.y : 0.2f * o.y;
            o.z = (o.z > 0.f) ? o.z : 0.2f * o.z;
            o.w = (o.w > 0.f) ? o.w : 0.2f * o.w;
            out4[ob + e[k]] = o;
        }
    }
}

extern "C" void kernel_launch(void* const* d_in, const int* in_sizes, int n_in,
                              void* d_out, int out_size, void* d_ws, size_t ws_size,
                              hipStream_t stream) {
    const float* in = (const float*)d_in[0];
    const float* wt = (const float*)d_in[1];
    const float* bs = (const float*)d_in[2];
    float* out = (float*)d_out;
    float* bb = (float*)d_ws;   // F_ * PLANE floats = 122,880 B

    k_bb<<<dim3(F_), dim3(256), 0, stream>>>(bs, bb);
    k_main<<<dim3(B_ * Dout_), dim3(NT), 0, stream>>>(in, wt, bb, out);
}

// Round 6
// 210.861 us; speedup vs baseline: 1.2015x; 1.2015x over previous
//
#include <hip/hip_runtime.h>

// inputs: (B=8, C=2, D=96, H=64, W=64) f32
// weight/bias: (F=8, C=2, d=3, h=60, w=64) f32
// out: (B=8, F=8, Dout=94, h=60, w=64) f32
#define B_ 8
#define C_ 2
#define D_ 96
#define H_ 64
#define W_ 64
#define F_ 8
#define KD 3
#define h_ 60
#define Dout_ 94
#define PLANE (h_ * W_)          // 3840 floats
#define NCH (PLANE / 4)          // 960 float4 per plane
#define NS2 (B_ * C_ * D_)       // 1536 s2 planes
#define S2_FLOATS ((size_t)NS2 * PLANE)
#define FT 4                     // f per k_main block
#define NFG (F_ / FT)            // 2

__device__ __forceinline__ float4 f4fma(float4 a, float4 b, float4 c) {
    c.x += a.x * b.x; c.y += a.y * b.y; c.z += a.z * b.z; c.w += a.w * b.w;
    return c;
}
__device__ __forceinline__ float4 f4add3(float4 a, float4 b, float4 c) {
    float4 o;
    o.x = a.x + b.x + c.x; o.y = a.y + b.y + c.y;
    o.z = a.z + b.z + c.z; o.w = a.w + b.w + c.w;
    return o;
}

// Horizontal 3-tap sum via lane shuffles; c4 = float4-column 0..15 within a
// 16-lane row group. Boundary columns contribute zero. Call from ALL lanes.
__device__ __forceinline__ float4 hsum3(float4 V, int c4) {
    const int lane = threadIdx.x & 63;
    float lw = __shfl(V.w, (lane + 63) & 63, 64);
    float rx = __shfl(V.x, (lane + 1) & 63, 64);
    if (c4 == 0) lw = 0.f;
    if (c4 == 15) rx = 0.f;
    float4 o;
    o.x = lw + V.x + V.y;
    o.y = V.x + V.y + V.z;
    o.z = V.y + V.z + V.w;
    o.w = V.z + V.w + rx;
    return o;
}

// ---------------------------------------------------------------------------
// Prep kernel (R3-proven):
// Blocks 0..NS2-1:       S2[b,c,p] = vertical 5-sum of input plane.
// Blocks NS2..NS2+F_-1:  bb[f]     = Box3x3( sum_{c,z} bias[f,c,z] ).
// ---------------------------------------------------------------------------
__global__ __launch_bounds__(256) void k_prep(const float* __restrict__ in,
                                              const float* __restrict__ bs,
                                              float* __restrict__ s2,
                                              float* __restrict__ bb) {
    const int bx = blockIdx.x;
    const int tid = threadIdx.x;
    __shared__ float4 lds[H_ * 16];  // 16 KB

    if (bx < NS2) {
        const float4* ip4 = (const float4*)(in + (size_t)bx * (H_ * W_));
        float4* op4 = (float4*)(s2 + (size_t)bx * PLANE);
#pragma unroll
        for (int k = 0; k < 4; ++k) lds[tid + 256 * k] = ip4[tid + 256 * k];
        __syncthreads();
#pragma unroll
        for (int k = 0; k < 4; ++k) {
            const int e = tid + 256 * k;
            if (e < NCH) {
                const int row = e >> 4, col = e & 15;
                float4 s = lds[row * 16 + col];
#pragma unroll
                for (int j = 1; j < 5; ++j) {
                    const float4 v = lds[(row + j) * 16 + col];
                    s.x += v.x; s.y += v.y; s.z += v.z; s.w += v.w;
                }
                op4[e] = s;
            }
        }
    } else {
        const int f = bx - NS2;
        float4* R = lds;  // rows 0..61, rows 0 and 61 zeroed
        if (tid < 32) {
            const int r = (tid >> 4) ? 61 : 0;
            R[r * 16 + (tid & 15)] = make_float4(0, 0, 0, 0);
        }
        const float4* bp = (const float4*)(bs + (size_t)f * (C_ * KD * PLANE));
#pragma unroll
        for (int k = 0; k < 4; ++k) {
            const int e = tid + 256 * k;
            if (e < NCH) {
                float4 s = make_float4(0, 0, 0, 0);
#pragma unroll
                for (int s6 = 0; s6 < 6; ++s6) {
                    const float4 v = bp[s6 * NCH + e];
                    s.x += v.x; s.y += v.y; s.z += v.z; s.w += v.w;
                }
                R[((e >> 4) + 1) * 16 + (e & 15)] = s;
            }
        }
        __syncthreads();
        float4* ob = (float4*)(bb + (size_t)f * PLANE);
#pragma unroll
        for (int k = 0; k < 4; ++k) {
            const int e = tid + 256 * k;
            int c4 = e & 15;
            float4 V = make_float4(0, 0, 0, 0);
            if (e < NCH) {
                const int row = e >> 4;
                V = f4add3(R[row * 16 + c4], R[(row + 1) * 16 + c4],
                           R[(row + 2) * 16 + c4]);
            }
            float4 o = hsum3(V, c4);
            if (e < NCH) ob[e] = o;
        }
    }
}

// ---------------------------------------------------------------------------
// Main kernel. Block = (b, dout, f-half); 256 threads; 1504 blocks.
// acc[4f][4chunks] = 64 VGPRs. Per (c,z) slice: 4 S2 chunk loads (L3),
// then 4 f x 4 weight-chunk FMAs (weights L2-resident, 1.5 MB total).
// Box per f: ping-pong LDS, 1 barrier/f, full contiguous plane store.
// ---------------------------------------------------------------------------
__global__ __launch_bounds__(256) void k_main(const float* __restrict__ s2,
                                              const float* __restrict__ wt,
                                              const float* __restrict__ bb,
                                              float* __restrict__ out) {
    const int bx = blockIdx.x;
    const int fg = bx & 1;
    const int dout = (bx >> 1) % Dout_;
    const int b = bx / (2 * Dout_);
    const int f0 = fg * FT;
    const int tid = threadIdx.x;

    __shared__ float4 Lb2[2][62 * 16];   // 31,744 B ping-pong box buffers

    int e[4], c4[4], row[4];
    bool act[4];
#pragma unroll
    for (int k = 0; k < 4; ++k) {
        e[k] = tid + 256 * k;
        row[k] = e[k] >> 4;
        c4[k] = e[k] & 15;
        act[k] = (e[k] < NCH);
    }

    const float4 z4 = make_float4(0, 0, 0, 0);
    float4 acc[FT][4];
#pragma unroll
    for (int fi = 0; fi < FT; ++fi)
#pragma unroll
        for (int k = 0; k < 4; ++k) acc[fi][k] = z4;

    const float4* s2f = (const float4*)s2;
    const float4* wt4 = (const float4*)wt;

#pragma unroll
    for (int c = 0; c < C_; ++c)
#pragma unroll
        for (int z = 0; z < KD; ++z) {
            const float4* sp = s2f + (size_t)((b * C_ + c) * D_ + dout + z) * NCH;
            float4 s2v[4];
#pragma unroll
            for (int k = 0; k < 4; ++k) s2v[k] = act[k] ? sp[e[k]] : z4;
#pragma unroll
            for (int fi = 0; fi < FT; ++fi) {
                const float4* wp =
                    wt4 + (size_t)(((f0 + fi) * C_ + c) * KD + z) * NCH;
#pragma unroll
                for (int k = 0; k < 4; ++k)
                    if (act[k]) acc[fi][k] = f4fma(wp[e[k]], s2v[k], acc[fi][k]);
            }
        }

    const float4* bb4 = (const float4*)bb;
    float4* out4 = (float4*)out;

    for (int fi = 0; fi < FT; ++fi) {
        const int f = f0 + fi;

        float4 bbv[4];
#pragma unroll
        for (int k = 0; k < 4; ++k)
            bbv[k] = act[k] ? bb4[(size_t)f * NCH + e[k]] : z4;

        float4* Lb = Lb2[fi & 1];
        if (fi < 2 && tid < 32) {   // zero halo rows (0 and 61) once per buffer
            const int r = (tid >> 4) ? 61 : 0;
            Lb[r * 16 + (tid & 15)] = z4;
        }
#pragma unroll
        for (int k = 0; k < 4; ++k)
            if (act[k]) Lb[(row[k] + 1) * 16 + c4[k]] = acc[fi][k];
        __syncthreads();            // single barrier per f (ping-pong)

        const size_t ob = (size_t)((b * F_ + f) * Dout_ + dout) * NCH;
#pragma unroll
        for (int k = 0; k < 4; ++k) {
            float4 V = z4;
            if (act[k])
                V = f4add3(Lb[row[k] * 16 + c4[k]],
                           Lb[(row[k] + 1) * 16 + c4[k]],
                           Lb[(row[k] + 2) * 16 + c4[k]]);
            float4 o = hsum3(V, c4[k]);   // uniform: no shuffle divergence
            if (act[k]) {
                o.x = 0.25f * (o.x + bbv[k].x);
                o.y = 0.25f * (o.y + bbv[k].y);
                o.z = 0.25f * (o.z + bbv[k].z);
                o.w = 0.25f * (o.w + bbv[k].w);
                o.x = (o.x > 0.f) ? o.x : 0.2f * o.x;
                o.y = (o.y > 0.f) ? o.y : 0.2f * o.y;
                o.z = (o.z > 0.f) ? o.z : 0.2f * o.z;
                o.w = (o.w > 0.f) ? o.w : 0.2f * o.w;
                out4[ob + e[k]] = o;
            }
        }
    }
}

extern "C" void kernel_launch(void* const* d_in, const int* in_sizes, int n_in,
                              void* d_out, int out_size, void* d_ws, size_t ws_size,
                              hipStream_t stream) {
    const float* in = (const float*)d_in[0];
    const float* wt = (const float*)d_in[1];
    const float* bs = (const float*)d_in[2];
    float* out = (float*)d_out;

    float* s2 = (float*)d_ws;        // 23.6 MB
    float* bb = s2 + S2_FLOATS;      // +123 KB

    k_prep<<<dim3(NS2 + F_), dim3(256), 0, stream>>>(in, bs, s2, bb);
    // grid: b(8) x dout(94) x f-half(2) = 1504 blocks
    k_main<<<dim3(B_ * Dout_ * NFG), dim3(256), 0, stream>>>(s2, wt, bb, out);
}